// Round 9
// baseline (605.846 us; speedup 1.0000x reference)
//
#include <hip/hip_runtime.h>

#define D 64
#define D4 (D / 4)         // 16 float4 per fp32 row
#define SBSHIFT 8          // 256 nodes per super-bucket
#define SBROWS 256
#define CHUNK_E 4096       // edges per chunk_sort block
#define STAGE_CAP 4608     // fine_sort staging entries
#define NCH_MAX 512
#define NSB_MAX 512

typedef float f32x4 __attribute__((ext_vector_type(4)));

__device__ __forceinline__ float elu1(float z) {
    return z > 0.0f ? z : expm1f(z);
}

// pack two fp32 -> bf16 pair (RNE), a in low 16, b in high 16
__device__ __forceinline__ unsigned int bfpair(float a, float b) {
    unsigned int ua = __float_as_uint(a);
    unsigned int ub = __float_as_uint(b);
    ua = (ua + 0x7FFFu + ((ua >> 16) & 1u)) >> 16;
    ub = (ub + 0x7FFFu + ((ub >> 16) & 1u)) & 0xFFFF0000u;
    return ub | ua;
}

__device__ __forceinline__ float bl16(int u) {
    return __uint_as_float((unsigned)u << 16);
}
__device__ __forceinline__ float bh16(int u) {
    return __uint_as_float((unsigned)u & 0xFFFF0000u);
}

// ---------- K1: fused emb + per-chunk LDS bucket sort (rep-instrumented) ------
__global__ __launch_bounds__(512) void chunk_emb_kernel(
        const float* __restrict__ x, const float* __restrict__ w,
        uint4* __restrict__ emb16,
        const int* __restrict__ src, const int* __restrict__ dst,
        int* __restrict__ slots_lin,
        int* __restrict__ cbase,
        int total8, int n_edges, int NSB, int rep) {
    __shared__ int hist[NSB_MAX], base[NSB_MAX], cur[NSB_MAX];
    __shared__ int wsum[8];
    __shared__ int stage[CHUNK_E];      // 16 KB
    const int tid = threadIdx.x;
    const int lane = tid & 63, wid = tid >> 6;

    #pragma unroll 1
    for (int r = 0; r < rep; ++r) {
    __syncthreads();                    // isolate reps (idempotent recompute)

    // ---- phase 0: emb16 = bf16(elu(x*w)), grid-stride ----
    hist[tid] = 0;
    const int gsz = gridDim.x * 512;
    for (int i = blockIdx.x * 512 + tid; i < total8; i += gsz) {
        f32x4 a = __builtin_nontemporal_load((const f32x4*)x + 2 * i);
        f32x4 b = __builtin_nontemporal_load((const f32x4*)x + 2 * i + 1);
        float4 wa = ((const float4*)w)[(2 * i) & 15];
        float4 wb = ((const float4*)w)[(2 * i + 1) & 15];
        uint4 o;
        o.x = bfpair(elu1(a.x * wa.x), elu1(a.y * wa.y));
        o.y = bfpair(elu1(a.z * wa.z), elu1(a.w * wa.w));
        o.z = bfpair(elu1(b.x * wb.x), elu1(b.y * wb.y));
        o.w = bfpair(elu1(b.z * wb.z), elu1(b.w * wb.w));
        emb16[i] = o;
    }

    // ---- chunk sort ----
    const int c0  = blockIdx.x * CHUNK_E;
    const int kn  = min(CHUNK_E, n_edges - c0);
    const int kn4 = kn >> 2;
    const int tail = kn & 3;
    __syncthreads();
    const int4* dst4 = (const int4*)(dst + c0);
    for (int k = tid; k < kn4; k += 512) {
        int4 dv = dst4[k];
        atomicAdd(&hist[dv.x >> SBSHIFT], 1);
        atomicAdd(&hist[dv.y >> SBSHIFT], 1);
        atomicAdd(&hist[dv.z >> SBSHIFT], 1);
        atomicAdd(&hist[dv.w >> SBSHIFT], 1);
    }
    if (tid < tail)
        atomicAdd(&hist[dst[c0 + (kn4 << 2) + tid] >> SBSHIFT], 1);
    __syncthreads();
    int h = hist[tid];
    int incl = h;
    #pragma unroll
    for (int off = 1; off < 64; off <<= 1) {
        int t = __shfl_up(incl, off, 64);
        if (lane >= off) incl += t;
    }
    if (lane == 63) wsum[wid] = incl;
    __syncthreads();
    {
        int pre = 0;
        for (int k = 0; k < wid; k++) pre += wsum[k];
        int e = pre + incl - h;
        base[tid] = e;
        cur[tid]  = e;
    }
    __syncthreads();
    const int4* src4 = (const int4*)(src + c0);
    for (int k = tid; k < kn4; k += 512) {
        int4 dv = dst4[k];
        int4 sv = src4[k];
        int pos;
        pos = atomicAdd(&cur[dv.x >> SBSHIFT], 1);
        stage[pos] = ((dv.x & (SBROWS - 1)) << 17) | sv.x;
        pos = atomicAdd(&cur[dv.y >> SBSHIFT], 1);
        stage[pos] = ((dv.y & (SBROWS - 1)) << 17) | sv.y;
        pos = atomicAdd(&cur[dv.z >> SBSHIFT], 1);
        stage[pos] = ((dv.z & (SBROWS - 1)) << 17) | sv.z;
        pos = atomicAdd(&cur[dv.w >> SBSHIFT], 1);
        stage[pos] = ((dv.w & (SBROWS - 1)) << 17) | sv.w;
    }
    if (tid < tail) {
        int k = (kn4 << 2) + tid;
        int d = dst[c0 + k], s = src[c0 + k];
        int pos = atomicAdd(&cur[d >> SBSHIFT], 1);
        stage[pos] = ((d & (SBROWS - 1)) << 17) | s;
    }
    __syncthreads();
    for (int j = tid; j < kn; j += 512)
        slots_lin[c0 + j] = stage[j];
    if (tid < NSB) cbase[blockIdx.x * (NSB + 1) + tid] = base[tid];
    if (tid == 0)  cbase[blockIdx.x * (NSB + 1) + NSB] = kn;
    }   // rep
}

// ---------- K2: per-sb LDS counting sort (rep-instrumented) ----
__global__ __launch_bounds__(512) void fine_sort_kernel(
        const int* __restrict__ slots_lin,
        const int* __restrict__ cbase,
        int* __restrict__ sorted2,
        int* __restrict__ node_off,
        int n_nodes, int NCH, int NSB, int rep) {
    __shared__ int rstart[NCH_MAX], rc[NCH_MAX];
    __shared__ int counts[SBROWS], cur[SBROWS];
    __shared__ int wsum[4], swa[8], swt[8];
    __shared__ int stage_out[STAGE_CAP];   // 18 KB
    const int s = blockIdx.x;
    const int tid = threadIdx.x;
    const int wid = tid >> 6, lane = tid & 63;
    const int sg = tid >> 4, l16 = tid & 15;

    #pragma unroll 1
    for (int r = 0; r < rep; ++r) {
    __syncthreads();                    // isolate reps

    int va = 0, vt = 0;
    if (tid < NCH) {
        int a = cbase[tid * (NSB + 1) + s];
        int b = cbase[tid * (NSB + 1) + s + 1];
        rstart[tid] = tid * CHUNK_E + a;
        rc[tid] = b - a;
        va = a;
        vt = b - a;
    }
    #pragma unroll
    for (int off = 1; off < 64; off <<= 1) {
        va += __shfl_xor(va, off, 64);
        vt += __shfl_xor(vt, off, 64);
    }
    if (lane == 0) { swa[wid] = va; swt[wid] = vt; }
    if (tid < SBROWS) counts[tid] = 0;
    __syncthreads();
    int sbb = 0, T = 0;
    #pragma unroll
    for (int k = 0; k < 8; k++) { sbb += swa[k]; T += swt[k]; }
    const bool fast = (T <= STAGE_CAP);
    for (int c = sg; c < NCH; c += 32) {
        int n = rc[c], st = rstart[c];
        for (int j = l16; j < n; j += 16)
            atomicAdd(&counts[((unsigned)slots_lin[st + j]) >> 17], 1);
    }
    __syncthreads();
    int v = 0, incl = 0;
    if (tid < SBROWS) {
        v = counts[tid];
        incl = v;
        #pragma unroll
        for (int off = 1; off < 64; off <<= 1) {
            int t = __shfl_up(incl, off, 64);
            if (lane >= off) incl += t;
        }
        if (lane == 63) wsum[wid] = incl;
    }
    __syncthreads();
    if (tid < SBROWS) {
        int pre = 0;
        for (int k = 0; k < wid; k++) pre += wsum[k];
        int e0 = pre + incl - v;
        cur[tid] = fast ? e0 : sbb + e0;
        int g0 = (s << SBSHIFT) + tid;
        if (g0 < n_nodes) node_off[g0] = sbb + e0;
    }
    if (s == gridDim.x - 1 && tid == 0) node_off[n_nodes] = sbb + T;
    __syncthreads();
    for (int c = sg; c < NCH; c += 32) {
        int n = rc[c], st = rstart[c];
        for (int j = l16; j < n; j += 16) {
            int pl = slots_lin[st + j];
            int r2 = ((unsigned)pl) >> 17;
            int pos = atomicAdd(&cur[r2], 1);
            if (fast) stage_out[pos] = pl & 0x1FFFF;
            else      sorted2[pos]   = pl & 0x1FFFF;
        }
    }
    __syncthreads();
    if (fast) {
        for (int i = tid; i < T; i += 512)
            sorted2[sbb + i] = stage_out[i];
    }
    }   // rep
}

// ---------- K3: gather (rep-instrumented) ----------
__device__ __forceinline__ int pick_idx(int p, int m0, int m1, int m2,
                                        const int* __restrict__ s2, int W0) {
    int a  = __shfl(m0, p & 63, 64);
    int b  = __shfl(m1, p & 63, 64);
    int cc = __shfl(m2, p & 63, 64);
    int r = p < 64 ? a : (p < 128 ? b : cc);
    if (p >= 192) r = s2[W0 + p];
    return r;
}

__global__ void gather_sum_kernel(const unsigned int* __restrict__ emb16,
                                  const int* __restrict__ sorted2,
                                  const int* __restrict__ node_off,
                                  float* __restrict__ out, int n_nodes,
                                  int rep) {
    const int wv = (blockIdx.x * blockDim.x + threadIdx.x) >> 6;
    const int lane = threadIdx.x & 63;
    const int g = lane >> 3;
    const int c = lane & 7;
    const int n0 = wv * 8;
    if (n0 >= n_nodes) return;        // wave-uniform exit
    const int n = n0 + g;

    #pragma unroll 1
    for (int r = 0; r < rep; ++r) {
    int beg = 0, end = 0;
    if (n < n_nodes) {
        beg = node_off[n];
        end = node_off[n + 1];
    }
    const int W0   = node_off[n0];
    const int Wend = node_off[min(n0 + 8, n_nodes)];
    const int T = Wend - W0;

    int m0 = 0, m1 = 0, m2 = 0;
    if (lane < T)       m0 = sorted2[W0 + lane];
    if (64 + lane < T)  m1 = sorted2[W0 + 64 + lane];
    if (128 + lane < T) m2 = sorted2[W0 + 128 + lane];

    const int4* row = (const int4*)emb16;
    const int pb = beg - W0;
    const int d = end - beg;
    int dmax = d;
    dmax = max(dmax, __shfl_xor(dmax, 8, 64));
    dmax = max(dmax, __shfl_xor(dmax, 16, 64));
    dmax = max(dmax, __shfl_xor(dmax, 32, 64));
    const int pclamp = T - 1;

    float acc[8] = {0.f, 0.f, 0.f, 0.f, 0.f, 0.f, 0.f, 0.f};

    int e = 0;
    for (; e + 4 <= dmax; e += 4) {
        int p0 = min(max(pb + e,     0), pclamp);
        int p1 = min(max(pb + e + 1, 0), pclamp);
        int p2 = min(max(pb + e + 2, 0), pclamp);
        int p3 = min(max(pb + e + 3, 0), pclamp);
        int i0 = pick_idx(p0, m0, m1, m2, sorted2, W0);
        int i1 = pick_idx(p1, m0, m1, m2, sorted2, W0);
        int i2 = pick_idx(p2, m0, m1, m2, sorted2, W0);
        int i3 = pick_idx(p3, m0, m1, m2, sorted2, W0);
        int4 u0 = make_int4(0, 0, 0, 0);
        int4 u1 = make_int4(0, 0, 0, 0);
        int4 u2 = make_int4(0, 0, 0, 0);
        int4 u3 = make_int4(0, 0, 0, 0);
        if (e < d)     u0 = row[i0 * 8 + c];
        if (e + 1 < d) u1 = row[i1 * 8 + c];
        if (e + 2 < d) u2 = row[i2 * 8 + c];
        if (e + 3 < d) u3 = row[i3 * 8 + c];
        acc[0] += bl16(u0.x) + bl16(u1.x) + bl16(u2.x) + bl16(u3.x);
        acc[1] += bh16(u0.x) + bh16(u1.x) + bh16(u2.x) + bh16(u3.x);
        acc[2] += bl16(u0.y) + bl16(u1.y) + bl16(u2.y) + bl16(u3.y);
        acc[3] += bh16(u0.y) + bh16(u1.y) + bh16(u2.y) + bh16(u3.y);
        acc[4] += bl16(u0.z) + bl16(u1.z) + bl16(u2.z) + bl16(u3.z);
        acc[5] += bh16(u0.z) + bh16(u1.z) + bh16(u2.z) + bh16(u3.z);
        acc[6] += bl16(u0.w) + bl16(u1.w) + bl16(u2.w) + bl16(u3.w);
        acc[7] += bh16(u0.w) + bh16(u1.w) + bh16(u2.w) + bh16(u3.w);
    }
    for (; e < dmax; ++e) {
        int p0 = min(max(pb + e, 0), pclamp);
        int i0 = pick_idx(p0, m0, m1, m2, sorted2, W0);
        if (e < d) {
            int4 u0 = row[i0 * 8 + c];
            acc[0] += bl16(u0.x); acc[1] += bh16(u0.x);
            acc[2] += bl16(u0.y); acc[3] += bh16(u0.y);
            acc[4] += bl16(u0.z); acc[5] += bh16(u0.z);
            acc[6] += bl16(u0.w); acc[7] += bh16(u0.w);
        }
    }

    if (n < n_nodes) {
        f32x4* out4 = (f32x4*)out;
        f32x4 o0 = {acc[0], acc[1], acc[2], acc[3]};
        f32x4 o1 = {acc[4], acc[5], acc[6], acc[7]};
        __builtin_nontemporal_store(o0, out4 + (size_t)n * D4 + c * 2);
        __builtin_nontemporal_store(o1, out4 + (size_t)n * D4 + c * 2 + 1);
    }
    }   // rep
}

// ---------- Fallback: atomic scatter ----------
__global__ void zero_out_kernel(float* __restrict__ out, int total4) {
    int i = blockIdx.x * blockDim.x + threadIdx.x;
    if (i < total4) ((float4*)out)[i] = make_float4(0.f, 0.f, 0.f, 0.f);
}

__global__ void scatter_fused_kernel(const float* __restrict__ x,
                                     const float* __restrict__ w,
                                     const int* __restrict__ src,
                                     const int* __restrict__ dst,
                                     float* __restrict__ out, int n_edges) {
    int t = blockIdx.x * blockDim.x + threadIdx.x;
    int e = t >> 4;
    int c = t & 15;
    if (e >= n_edges) return;
    int s = src[e];
    int d = dst[e];
    float4 xv = ((const float4*)x)[s * D4 + c];
    float4 wv = ((const float4*)w)[c];
    float* o = out + d * D + c * 4;
    unsafeAtomicAdd(o + 0, elu1(xv.x * wv.x));
    unsafeAtomicAdd(o + 1, elu1(xv.y * wv.y));
    unsafeAtomicAdd(o + 2, elu1(xv.z * wv.z));
    unsafeAtomicAdd(o + 3, elu1(xv.w * wv.w));
}

extern "C" void kernel_launch(void* const* d_in, const int* in_sizes, int n_in,
                              void* d_out, int out_size, void* d_ws, size_t ws_size,
                              hipStream_t stream) {
    const float* x   = (const float*)d_in[0];   // [N, 64] fp32
    const float* w   = (const float*)d_in[1];   // [1, 64] fp32
    const int*   src = (const int*)d_in[2];     // [E] int32
    const int*   dst = (const int*)d_in[3];     // [E] int32
    float* out = (float*)d_out;

    const int n_nodes = in_sizes[0] / D;
    const int n_edges = in_sizes[2];
    const int total4  = n_nodes * D4;
    const int total8  = n_nodes * 8;
    const int block = 256;

    const int NSB = (n_nodes + SBROWS - 1) >> SBSHIFT;
    const int NCH = (n_edges + CHUNK_E - 1) / CHUNK_E;

    auto align16 = [](size_t v) { return (v + 15) & ~size_t(15); };
    const size_t emb_b      = align16((size_t)n_nodes * D * 2);          // bf16
    const size_t slots_b    = align16((size_t)NCH * CHUNK_E * 4);
    const size_t cbase_b    = align16((size_t)NCH * (NSB + 1) * 4);
    const size_t sorted2_b  = align16((size_t)n_edges * 4);
    const size_t nodeoff_b  = align16((size_t)(n_nodes + 1) * 4);
    const size_t need = emb_b + slots_b + cbase_b + sorted2_b + nodeoff_b;

    if (ws_size >= need && n_nodes <= 131072 && NSB <= NSB_MAX && NCH <= NCH_MAX) {
        char* p = (char*)d_ws;
        unsigned int* emb16 = (unsigned int*)p;  p += emb_b;
        int* slots_lin = (int*)p;  p += slots_b;
        int* cbase     = (int*)p;  p += cbase_b;
        int* sorted2   = (int*)p;  p += sorted2_b;
        int* node_off  = (int*)p;

        // INSTRUMENTED: rep counts 8/11/10 make each dispatch > 250 µs so all
        // three appear above the harness fills in the rocprof top-5.
        chunk_emb_kernel<<<NCH, 512, 0, stream>>>(
            x, w, (uint4*)emb16, src, dst, slots_lin, cbase,
            total8, n_edges, NSB, 8);
        fine_sort_kernel<<<NSB, 512, 0, stream>>>(
            slots_lin, cbase, sorted2, node_off, n_nodes, NCH, NSB, 11);
        const int nwaves = (n_nodes + 7) / 8;
        const int gblocks = (nwaves * 64 + block - 1) / block;
        gather_sum_kernel<<<gblocks, block, 0, stream>>>(
            emb16, sorted2, node_off, out, n_nodes, 10);
    } else {
        zero_out_kernel<<<(total4 + block - 1) / block, block, 0, stream>>>(out, total4);
        const int nt = n_edges * 16;
        scatter_fused_kernel<<<(nt + block - 1) / block, block, 0, stream>>>(
            x, w, src, dst, out, n_edges);
    }
}

// Round 10
// 153.217 us; speedup vs baseline: 3.9542x; 3.9542x over previous
//
#include <hip/hip_runtime.h>

#define D 64
#define D4 (D / 4)         // 16 float4 per fp32 row
#define SBSHIFT 8          // 256 nodes per super-bucket
#define SBROWS 256
#define CHUNK_E 4096       // edges per chunk_sort block
#define STAGE_CAP 4608     // fine_sort staging entries
#define NCH_MAX 512
#define NSB_MAX 512
#define EMB_BLOCKS 192     // dedicated emb-role blocks co-resident with sort

typedef float f32x4 __attribute__((ext_vector_type(4)));

__device__ __forceinline__ float elu1(float z) {
    return z > 0.0f ? z : expm1f(z);
}

// pack two fp32 -> bf16 pair (RNE), a in low 16, b in high 16
__device__ __forceinline__ unsigned int bfpair(float a, float b) {
    unsigned int ua = __float_as_uint(a);
    unsigned int ub = __float_as_uint(b);
    ua = (ua + 0x7FFFu + ((ua >> 16) & 1u)) >> 16;
    ub = (ub + 0x7FFFu + ((ub >> 16) & 1u)) & 0xFFFF0000u;
    return ub | ua;
}

__device__ __forceinline__ float bl16(int u) {
    return __uint_as_float((unsigned)u << 16);
}
__device__ __forceinline__ float bh16(int u) {
    return __uint_as_float((unsigned)u & 0xFFFF0000u);
}

// ---------- K1: role-split blocks.  bid < NCH: per-chunk LDS bucket sort.
//   bid >= NCH: emb streaming (fills the sort blocks' barrier bubbles).
//   emb16 is stored as TWO column planes of 64 B/node (cols 0-31 | 32-63) so
//   gather phases have an L2-fittable 6.4 MB working set. ----------
__global__ __launch_bounds__(512) void chunk_emb_kernel(
        const float* __restrict__ x, const float* __restrict__ w,
        unsigned int* __restrict__ emb16,     // [2][n_nodes*16] uint (planes)
        const int* __restrict__ src, const int* __restrict__ dst,
        int* __restrict__ slots_lin,
        int* __restrict__ cbase,
        int total8, int n_edges, int NSB, int NCH, int n_nodes) {
    __shared__ int hist[NSB_MAX], base[NSB_MAX], cur[NSB_MAX];
    __shared__ int wsum[8];
    __shared__ int stage[CHUNK_E];      // 16 KB
    const int tid = threadIdx.x;
    const int lane = tid & 63, wid = tid >> 6;
    const int bid = blockIdx.x;

    if (bid >= NCH) {
        // ---- emb role: grid-stride, no barriers ----
        uint4* p0 = (uint4*)emb16;                             // plane 0
        uint4* p1 = (uint4*)(emb16 + (size_t)n_nodes * 16);    // plane 1
        for (int i = (bid - NCH) * 512 + tid; i < total8; i += EMB_BLOCKS * 512) {
            const int n = i >> 3, c = i & 7;
            f32x4 a = __builtin_nontemporal_load((const f32x4*)x + 2 * i);
            f32x4 b = __builtin_nontemporal_load((const f32x4*)x + 2 * i + 1);
            float4 wa = ((const float4*)w)[(2 * i) & 15];
            float4 wb = ((const float4*)w)[(2 * i + 1) & 15];
            uint4 o;
            o.x = bfpair(elu1(a.x * wa.x), elu1(a.y * wa.y));
            o.y = bfpair(elu1(a.z * wa.z), elu1(a.w * wa.w));
            o.z = bfpair(elu1(b.x * wb.x), elu1(b.y * wb.y));
            o.w = bfpair(elu1(b.z * wb.z), elu1(b.w * wb.w));
            uint4* pl = (c < 4) ? p0 : p1;
            pl[n * 4 + (c & 3)] = o;
        }
        return;
    }

    // ---- sort role ----
    hist[tid] = 0;
    const int c0  = bid * CHUNK_E;
    const int kn  = min(CHUNK_E, n_edges - c0);
    const int kn4 = kn >> 2;
    const int tail = kn & 3;
    __syncthreads();
    const int4* dst4 = (const int4*)(dst + c0);
    for (int k = tid; k < kn4; k += 512) {
        int4 dv = dst4[k];
        atomicAdd(&hist[dv.x >> SBSHIFT], 1);
        atomicAdd(&hist[dv.y >> SBSHIFT], 1);
        atomicAdd(&hist[dv.z >> SBSHIFT], 1);
        atomicAdd(&hist[dv.w >> SBSHIFT], 1);
    }
    if (tid < tail)
        atomicAdd(&hist[dst[c0 + (kn4 << 2) + tid] >> SBSHIFT], 1);
    __syncthreads();
    int h = hist[tid];
    int incl = h;
    #pragma unroll
    for (int off = 1; off < 64; off <<= 1) {
        int t = __shfl_up(incl, off, 64);
        if (lane >= off) incl += t;
    }
    if (lane == 63) wsum[wid] = incl;
    __syncthreads();
    {
        int pre = 0;
        for (int k = 0; k < wid; k++) pre += wsum[k];
        int e = pre + incl - h;
        base[tid] = e;
        cur[tid]  = e;
    }
    __syncthreads();
    const int4* src4 = (const int4*)(src + c0);
    for (int k = tid; k < kn4; k += 512) {
        int4 dv = dst4[k];
        int4 sv = src4[k];
        int pos;
        pos = atomicAdd(&cur[dv.x >> SBSHIFT], 1);
        stage[pos] = ((dv.x & (SBROWS - 1)) << 17) | sv.x;
        pos = atomicAdd(&cur[dv.y >> SBSHIFT], 1);
        stage[pos] = ((dv.y & (SBROWS - 1)) << 17) | sv.y;
        pos = atomicAdd(&cur[dv.z >> SBSHIFT], 1);
        stage[pos] = ((dv.z & (SBROWS - 1)) << 17) | sv.z;
        pos = atomicAdd(&cur[dv.w >> SBSHIFT], 1);
        stage[pos] = ((dv.w & (SBROWS - 1)) << 17) | sv.w;
    }
    if (tid < tail) {
        int k = (kn4 << 2) + tid;
        int d = dst[c0 + k], s = src[c0 + k];
        int pos = atomicAdd(&cur[d >> SBSHIFT], 1);
        stage[pos] = ((d & (SBROWS - 1)) << 17) | s;
    }
    __syncthreads();
    for (int j = tid; j < kn; j += 512)
        slots_lin[c0 + j] = stage[j];
    if (tid < NSB) cbase[bid * (NSB + 1) + tid] = base[tid];
    if (tid == 0)  cbase[bid * (NSB + 1) + NSB] = kn;
}

// ---------- K2: per-sb LDS counting sort -> sorted2 + node_off (unchanged) ----
__global__ __launch_bounds__(512) void fine_sort_kernel(
        const int* __restrict__ slots_lin,
        const int* __restrict__ cbase,
        int* __restrict__ sorted2,
        int* __restrict__ node_off,
        int n_nodes, int NCH, int NSB) {
    __shared__ int rstart[NCH_MAX], rc[NCH_MAX];
    __shared__ int counts[SBROWS], cur[SBROWS];
    __shared__ int wsum[4], swa[8], swt[8];
    __shared__ int stage_out[STAGE_CAP];   // 18 KB
    const int s = blockIdx.x;
    const int tid = threadIdx.x;
    const int wid = tid >> 6, lane = tid & 63;
    const int sg = tid >> 4, l16 = tid & 15;

    int va = 0, vt = 0;
    if (tid < NCH) {
        int a = cbase[tid * (NSB + 1) + s];
        int b = cbase[tid * (NSB + 1) + s + 1];
        rstart[tid] = tid * CHUNK_E + a;
        rc[tid] = b - a;
        va = a;
        vt = b - a;
    }
    #pragma unroll
    for (int off = 1; off < 64; off <<= 1) {
        va += __shfl_xor(va, off, 64);
        vt += __shfl_xor(vt, off, 64);
    }
    if (lane == 0) { swa[wid] = va; swt[wid] = vt; }
    if (tid < SBROWS) counts[tid] = 0;
    __syncthreads();
    int sbb = 0, T = 0;
    #pragma unroll
    for (int k = 0; k < 8; k++) { sbb += swa[k]; T += swt[k]; }
    const bool fast = (T <= STAGE_CAP);
    for (int c = sg; c < NCH; c += 32) {
        int n = rc[c], st = rstart[c];
        for (int j = l16; j < n; j += 16)
            atomicAdd(&counts[((unsigned)slots_lin[st + j]) >> 17], 1);
    }
    __syncthreads();
    int v = 0, incl = 0;
    if (tid < SBROWS) {
        v = counts[tid];
        incl = v;
        #pragma unroll
        for (int off = 1; off < 64; off <<= 1) {
            int t = __shfl_up(incl, off, 64);
            if (lane >= off) incl += t;
        }
        if (lane == 63) wsum[wid] = incl;
    }
    __syncthreads();
    if (tid < SBROWS) {
        int pre = 0;
        for (int k = 0; k < wid; k++) pre += wsum[k];
        int e0 = pre + incl - v;
        cur[tid] = fast ? e0 : sbb + e0;
        int g0 = (s << SBSHIFT) + tid;
        if (g0 < n_nodes) node_off[g0] = sbb + e0;
    }
    if (s == gridDim.x - 1 && tid == 0) node_off[n_nodes] = sbb + T;
    __syncthreads();
    for (int c = sg; c < NCH; c += 32) {
        int n = rc[c], st = rstart[c];
        for (int j = l16; j < n; j += 16) {
            int pl = slots_lin[st + j];
            int r2 = ((unsigned)pl) >> 17;
            int pos = atomicAdd(&cur[r2], 1);
            if (fast) stage_out[pos] = pl & 0x1FFFF;
            else      sorted2[pos]   = pl & 0x1FFFF;
        }
    }
    __syncthreads();
    if (fast) {
        for (int i = tid; i < T; i += 512)
            sorted2[sbb + i] = stage_out[i];
    }
}

// ---------- K3: plane-phased gather.  blocks [0,pbk): plane 0 (cols 0-31);
//   blocks [pbk,2*pbk): plane 1.  Per phase the row working set is 6.4 MB ->
//   L2-fittable -> cuts the 72 MB duplicated fetch.  8 nodes/wave, 8 lanes/node,
//   8B half-row loads, lane-local accumulation, all-lane shuffles. ----------
__device__ __forceinline__ int pick_idx(int p, int m0, int m1, int m2,
                                        const int* __restrict__ s2, int W0) {
    int a  = __shfl(m0, p & 63, 64);
    int b  = __shfl(m1, p & 63, 64);
    int cc = __shfl(m2, p & 63, 64);
    int r = p < 64 ? a : (p < 128 ? b : cc);
    if (p >= 192) r = s2[W0 + p];
    return r;
}

__global__ void gather_sum_kernel(const unsigned int* __restrict__ emb16,
                                  const int* __restrict__ sorted2,
                                  const int* __restrict__ node_off,
                                  float* __restrict__ out, int n_nodes,
                                  int pbk) {
    const int plane = (blockIdx.x >= pbk) ? 1 : 0;
    const int lb = blockIdx.x - plane * pbk;
    const int wv = (lb * (int)blockDim.x + (int)threadIdx.x) >> 6;
    const int lane = threadIdx.x & 63;
    const int g = lane >> 3;          // node slot within wave
    const int c = lane & 7;           // int2 chunk within 64B half-row
    const int n0 = wv * 8;
    if (n0 >= n_nodes) return;        // wave-uniform exit
    const int n = n0 + g;

    int beg = 0, end = 0;
    if (n < n_nodes) {
        beg = node_off[n];
        end = node_off[n + 1];
    }
    const int W0   = node_off[n0];
    const int Wend = node_off[min(n0 + 8, n_nodes)];
    const int T = Wend - W0;

    int m0 = 0, m1 = 0, m2 = 0;
    if (lane < T)       m0 = sorted2[W0 + lane];
    if (64 + lane < T)  m1 = sorted2[W0 + 64 + lane];
    if (128 + lane < T) m2 = sorted2[W0 + 128 + lane];

    const int2* rowh = (const int2*)(emb16 + (size_t)plane * (size_t)n_nodes * 16);
    const int pb = beg - W0;
    const int d = end - beg;
    int dmax = d;
    dmax = max(dmax, __shfl_xor(dmax, 8, 64));
    dmax = max(dmax, __shfl_xor(dmax, 16, 64));
    dmax = max(dmax, __shfl_xor(dmax, 32, 64));
    const int pclamp = T - 1;

    float a0 = 0.f, a1 = 0.f, a2 = 0.f, a3 = 0.f;

    int e = 0;
    for (; e + 4 <= dmax; e += 4) {
        int p0 = min(max(pb + e,     0), pclamp);
        int p1 = min(max(pb + e + 1, 0), pclamp);
        int p2 = min(max(pb + e + 2, 0), pclamp);
        int p3 = min(max(pb + e + 3, 0), pclamp);
        int i0 = pick_idx(p0, m0, m1, m2, sorted2, W0);
        int i1 = pick_idx(p1, m0, m1, m2, sorted2, W0);
        int i2 = pick_idx(p2, m0, m1, m2, sorted2, W0);
        int i3 = pick_idx(p3, m0, m1, m2, sorted2, W0);
        int2 u0 = make_int2(0, 0);
        int2 u1 = make_int2(0, 0);
        int2 u2 = make_int2(0, 0);
        int2 u3 = make_int2(0, 0);
        if (e < d)     u0 = rowh[i0 * 8 + c];
        if (e + 1 < d) u1 = rowh[i1 * 8 + c];
        if (e + 2 < d) u2 = rowh[i2 * 8 + c];
        if (e + 3 < d) u3 = rowh[i3 * 8 + c];
        a0 += bl16(u0.x) + bl16(u1.x) + bl16(u2.x) + bl16(u3.x);
        a1 += bh16(u0.x) + bh16(u1.x) + bh16(u2.x) + bh16(u3.x);
        a2 += bl16(u0.y) + bl16(u1.y) + bl16(u2.y) + bl16(u3.y);
        a3 += bh16(u0.y) + bh16(u1.y) + bh16(u2.y) + bh16(u3.y);
    }
    for (; e < dmax; ++e) {
        int p0 = min(max(pb + e, 0), pclamp);
        int i0 = pick_idx(p0, m0, m1, m2, sorted2, W0);
        if (e < d) {
            int2 u0 = rowh[i0 * 8 + c];
            a0 += bl16(u0.x); a1 += bh16(u0.x);
            a2 += bl16(u0.y); a3 += bh16(u0.y);
        }
    }

    if (n < n_nodes) {
        f32x4* out4 = (f32x4*)out;
        f32x4 o = {a0, a1, a2, a3};
        __builtin_nontemporal_store(o, out4 + (size_t)n * D4 + plane * 8 + c);
    }
}

// ---------- Fallback: atomic scatter ----------
__global__ void zero_out_kernel(float* __restrict__ out, int total4) {
    int i = blockIdx.x * blockDim.x + threadIdx.x;
    if (i < total4) ((float4*)out)[i] = make_float4(0.f, 0.f, 0.f, 0.f);
}

__global__ void scatter_fused_kernel(const float* __restrict__ x,
                                     const float* __restrict__ w,
                                     const int* __restrict__ src,
                                     const int* __restrict__ dst,
                                     float* __restrict__ out, int n_edges) {
    int t = blockIdx.x * blockDim.x + threadIdx.x;
    int e = t >> 4;
    int c = t & 15;
    if (e >= n_edges) return;
    int s = src[e];
    int d = dst[e];
    float4 xv = ((const float4*)x)[s * D4 + c];
    float4 wv = ((const float4*)w)[c];
    float* o = out + d * D + c * 4;
    unsafeAtomicAdd(o + 0, elu1(xv.x * wv.x));
    unsafeAtomicAdd(o + 1, elu1(xv.y * wv.y));
    unsafeAtomicAdd(o + 2, elu1(xv.z * wv.z));
    unsafeAtomicAdd(o + 3, elu1(xv.w * wv.w));
}

extern "C" void kernel_launch(void* const* d_in, const int* in_sizes, int n_in,
                              void* d_out, int out_size, void* d_ws, size_t ws_size,
                              hipStream_t stream) {
    const float* x   = (const float*)d_in[0];   // [N, 64] fp32
    const float* w   = (const float*)d_in[1];   // [1, 64] fp32
    const int*   src = (const int*)d_in[2];     // [E] int32
    const int*   dst = (const int*)d_in[3];     // [E] int32
    float* out = (float*)d_out;

    const int n_nodes = in_sizes[0] / D;
    const int n_edges = in_sizes[2];
    const int total4  = n_nodes * D4;
    const int total8  = n_nodes * 8;
    const int block = 256;

    const int NSB = (n_nodes + SBROWS - 1) >> SBSHIFT;
    const int NCH = (n_edges + CHUNK_E - 1) / CHUNK_E;

    auto align16 = [](size_t v) { return (v + 15) & ~size_t(15); };
    const size_t emb_b      = align16((size_t)n_nodes * D * 2);          // bf16 (2 planes)
    const size_t slots_b    = align16((size_t)NCH * CHUNK_E * 4);
    const size_t cbase_b    = align16((size_t)NCH * (NSB + 1) * 4);
    const size_t sorted2_b  = align16((size_t)n_edges * 4);
    const size_t nodeoff_b  = align16((size_t)(n_nodes + 1) * 4);
    const size_t need = emb_b + slots_b + cbase_b + sorted2_b + nodeoff_b;

    if (ws_size >= need && n_nodes <= 131072 && NSB <= NSB_MAX && NCH <= NCH_MAX) {
        char* p = (char*)d_ws;
        unsigned int* emb16 = (unsigned int*)p;  p += emb_b;
        int* slots_lin = (int*)p;  p += slots_b;
        int* cbase     = (int*)p;  p += cbase_b;
        int* sorted2   = (int*)p;  p += sorted2_b;
        int* node_off  = (int*)p;

        chunk_emb_kernel<<<NCH + EMB_BLOCKS, 512, 0, stream>>>(
            x, w, emb16, src, dst, slots_lin, cbase,
            total8, n_edges, NSB, NCH, n_nodes);
        fine_sort_kernel<<<NSB, 512, 0, stream>>>(
            slots_lin, cbase, sorted2, node_off, n_nodes, NCH, NSB);
        const int nwaves = (n_nodes + 7) / 8;
        const int pbk = (nwaves * 64 + block - 1) / block;   // blocks per plane
        gather_sum_kernel<<<2 * pbk, block, 0, stream>>>(
            emb16, sorted2, node_off, out, n_nodes, pbk);
    } else {
        zero_out_kernel<<<(total4 + block - 1) / block, block, 0, stream>>>(out, total4);
        const int nt = n_edges * 16;
        scatter_fused_kernel<<<(nt + block - 1) / block, block, 0, stream>>>(
            x, w, src, dst, out, n_edges);
    }
}

// Round 11
// 144.045 us; speedup vs baseline: 4.2060x; 1.0637x over previous
//
#include <hip/hip_runtime.h>

#define D 64
#define D4 (D / 4)         // 16 float4 per fp32 row
#define SBSHIFT 8          // 256 nodes per super-bucket
#define SBROWS 256
#define CHUNK_E 4096       // edges per chunk_sort block
#define STAGE_CAP 4608     // fine_sort staging entries
#define NCH_MAX 512
#define NSB_MAX 512
#define WIN 192            // per-wave LDS index-window capacity

typedef float f32x4 __attribute__((ext_vector_type(4)));

__device__ __forceinline__ float elu1(float z) {
    return z > 0.0f ? z : expm1f(z);
}

// pack two fp32 -> bf16 pair (RNE), a in low 16, b in high 16
__device__ __forceinline__ unsigned int bfpair(float a, float b) {
    unsigned int ua = __float_as_uint(a);
    unsigned int ub = __float_as_uint(b);
    ua = (ua + 0x7FFFu + ((ua >> 16) & 1u)) >> 16;
    ub = (ub + 0x7FFFu + ((ub >> 16) & 1u)) & 0xFFFF0000u;
    return ub | ua;
}

__device__ __forceinline__ float bl16(int u) {
    return __uint_as_float((unsigned)u << 16);
}
__device__ __forceinline__ float bh16(int u) {
    return __uint_as_float((unsigned)u & 0xFFFF0000u);
}

// ---------- K1: fused emb (grid-stride phase 0) + per-chunk LDS bucket sort ---
__global__ __launch_bounds__(512) void chunk_emb_kernel(
        const float* __restrict__ x, const float* __restrict__ w,
        uint4* __restrict__ emb16,
        const int* __restrict__ src, const int* __restrict__ dst,
        int* __restrict__ slots_lin,
        int* __restrict__ cbase,
        int total8, int n_edges, int NSB) {
    __shared__ int hist[NSB_MAX], base[NSB_MAX], cur[NSB_MAX];
    __shared__ int wsum[8];
    __shared__ int stage[CHUNK_E];      // 16 KB
    const int tid = threadIdx.x;
    const int lane = tid & 63, wid = tid >> 6;

    // ---- phase 0: emb16 = bf16(elu(x*w)), grid-stride ----
    hist[tid] = 0;
    const int gsz = gridDim.x * 512;
    for (int i = blockIdx.x * 512 + tid; i < total8; i += gsz) {
        f32x4 a = __builtin_nontemporal_load((const f32x4*)x + 2 * i);
        f32x4 b = __builtin_nontemporal_load((const f32x4*)x + 2 * i + 1);
        float4 wa = ((const float4*)w)[(2 * i) & 15];
        float4 wb = ((const float4*)w)[(2 * i + 1) & 15];
        uint4 o;
        o.x = bfpair(elu1(a.x * wa.x), elu1(a.y * wa.y));
        o.y = bfpair(elu1(a.z * wa.z), elu1(a.w * wa.w));
        o.z = bfpair(elu1(b.x * wb.x), elu1(b.y * wb.y));
        o.w = bfpair(elu1(b.z * wb.z), elu1(b.w * wb.w));
        emb16[i] = o;
    }

    // ---- chunk sort ----
    const int c0  = blockIdx.x * CHUNK_E;
    const int kn  = min(CHUNK_E, n_edges - c0);
    const int kn4 = kn >> 2;
    const int tail = kn & 3;
    __syncthreads();
    const int4* dst4 = (const int4*)(dst + c0);
    for (int k = tid; k < kn4; k += 512) {
        int4 dv = dst4[k];
        atomicAdd(&hist[dv.x >> SBSHIFT], 1);
        atomicAdd(&hist[dv.y >> SBSHIFT], 1);
        atomicAdd(&hist[dv.z >> SBSHIFT], 1);
        atomicAdd(&hist[dv.w >> SBSHIFT], 1);
    }
    if (tid < tail)
        atomicAdd(&hist[dst[c0 + (kn4 << 2) + tid] >> SBSHIFT], 1);
    __syncthreads();
    int h = hist[tid];
    int incl = h;
    #pragma unroll
    for (int off = 1; off < 64; off <<= 1) {
        int t = __shfl_up(incl, off, 64);
        if (lane >= off) incl += t;
    }
    if (lane == 63) wsum[wid] = incl;
    __syncthreads();
    {
        int pre = 0;
        for (int k = 0; k < wid; k++) pre += wsum[k];
        int e = pre + incl - h;
        base[tid] = e;
        cur[tid]  = e;
    }
    __syncthreads();
    const int4* src4 = (const int4*)(src + c0);
    for (int k = tid; k < kn4; k += 512) {
        int4 dv = dst4[k];
        int4 sv = src4[k];
        int pos;
        pos = atomicAdd(&cur[dv.x >> SBSHIFT], 1);
        stage[pos] = ((dv.x & (SBROWS - 1)) << 17) | sv.x;
        pos = atomicAdd(&cur[dv.y >> SBSHIFT], 1);
        stage[pos] = ((dv.y & (SBROWS - 1)) << 17) | sv.y;
        pos = atomicAdd(&cur[dv.z >> SBSHIFT], 1);
        stage[pos] = ((dv.z & (SBROWS - 1)) << 17) | sv.z;
        pos = atomicAdd(&cur[dv.w >> SBSHIFT], 1);
        stage[pos] = ((dv.w & (SBROWS - 1)) << 17) | sv.w;
    }
    if (tid < tail) {
        int k = (kn4 << 2) + tid;
        int d = dst[c0 + k], s = src[c0 + k];
        int pos = atomicAdd(&cur[d >> SBSHIFT], 1);
        stage[pos] = ((d & (SBROWS - 1)) << 17) | s;
    }
    __syncthreads();
    for (int j = tid; j < kn; j += 512)
        slots_lin[c0 + j] = stage[j];
    if (tid < NSB) cbase[blockIdx.x * (NSB + 1) + tid] = base[tid];
    if (tid == 0)  cbase[blockIdx.x * (NSB + 1) + NSB] = kn;
}

// ---------- K2: per-sb LDS counting sort -> sorted2 + node_off ----
__global__ __launch_bounds__(512) void fine_sort_kernel(
        const int* __restrict__ slots_lin,
        const int* __restrict__ cbase,
        int* __restrict__ sorted2,
        int* __restrict__ node_off,
        int n_nodes, int NCH, int NSB) {
    __shared__ int rstart[NCH_MAX], rc[NCH_MAX];
    __shared__ int counts[SBROWS], cur[SBROWS];
    __shared__ int wsum[4], swa[8], swt[8];
    __shared__ int stage_out[STAGE_CAP];   // 18 KB
    const int s = blockIdx.x;
    const int tid = threadIdx.x;
    const int wid = tid >> 6, lane = tid & 63;
    const int sg = tid >> 4, l16 = tid & 15;

    int va = 0, vt = 0;
    if (tid < NCH) {
        int a = cbase[tid * (NSB + 1) + s];
        int b = cbase[tid * (NSB + 1) + s + 1];
        rstart[tid] = tid * CHUNK_E + a;
        rc[tid] = b - a;
        va = a;
        vt = b - a;
    }
    #pragma unroll
    for (int off = 1; off < 64; off <<= 1) {
        va += __shfl_xor(va, off, 64);
        vt += __shfl_xor(vt, off, 64);
    }
    if (lane == 0) { swa[wid] = va; swt[wid] = vt; }
    if (tid < SBROWS) counts[tid] = 0;
    __syncthreads();
    int sbb = 0, T = 0;
    #pragma unroll
    for (int k = 0; k < 8; k++) { sbb += swa[k]; T += swt[k]; }
    const bool fast = (T <= STAGE_CAP);
    for (int c = sg; c < NCH; c += 32) {
        int n = rc[c], st = rstart[c];
        for (int j = l16; j < n; j += 16)
            atomicAdd(&counts[((unsigned)slots_lin[st + j]) >> 17], 1);
    }
    __syncthreads();
    int v = 0, incl = 0;
    if (tid < SBROWS) {
        v = counts[tid];
        incl = v;
        #pragma unroll
        for (int off = 1; off < 64; off <<= 1) {
            int t = __shfl_up(incl, off, 64);
            if (lane >= off) incl += t;
        }
        if (lane == 63) wsum[wid] = incl;
    }
    __syncthreads();
    if (tid < SBROWS) {
        int pre = 0;
        for (int k = 0; k < wid; k++) pre += wsum[k];
        int e0 = pre + incl - v;
        cur[tid] = fast ? e0 : sbb + e0;
        int g0 = (s << SBSHIFT) + tid;
        if (g0 < n_nodes) node_off[g0] = sbb + e0;
    }
    if (s == gridDim.x - 1 && tid == 0) node_off[n_nodes] = sbb + T;
    __syncthreads();
    for (int c = sg; c < NCH; c += 32) {
        int n = rc[c], st = rstart[c];
        for (int j = l16; j < n; j += 16) {
            int pl = slots_lin[st + j];
            int r2 = ((unsigned)pl) >> 17;
            int pos = atomicAdd(&cur[r2], 1);
            if (fast) stage_out[pos] = pl & 0x1FFFF;
            else      sorted2[pos]   = pl & 0x1FFFF;
        }
    }
    __syncthreads();
    if (fast) {
        for (int i = tid; i < T; i += 512)
            sorted2[sbb + i] = stage_out[i];
    }
}

// ---------- K3: 8 nodes/wave, 8 lanes/node; per-wave LDS index window
//   (1 ds_read per index, broadcast within group — replaces 3 bpermutes);
//   8 row-loads in flight.  No shuffles in inner loop -> no divergence
//   hazard; LDS reads clamp-guarded, row loads predicated on e<d. ----------
__global__ __launch_bounds__(256) void gather_sum_kernel(
        const unsigned int* __restrict__ emb16,
        const int* __restrict__ sorted2,
        const int* __restrict__ node_off,
        float* __restrict__ out, int n_nodes) {
    __shared__ int win[4][WIN];          // 3 KB: 4 waves x 192 indices
    const int tid = threadIdx.x;
    const int wwid = tid >> 6;           // wave within block
    const int lane = tid & 63;
    const int wv = (blockIdx.x * 256 + tid) >> 6;
    const int g = lane >> 3;             // node slot within wave
    const int c = lane & 7;              // int4 chunk within 128B row
    const int n0 = wv * 8;
    if (n0 >= n_nodes) return;           // wave-uniform exit
    const int n = n0 + g;

    int beg = 0, end = 0;
    if (n < n_nodes) {
        beg = node_off[n];
        end = node_off[n + 1];
    }
    const int W0   = node_off[n0];
    const int Wend = node_off[min(n0 + 8, n_nodes)];
    const int T = Wend - W0;

    // stage this wave's contiguous index window into LDS (coalesced)
    const int Tc = min(T, WIN);
    for (int t = lane; t < Tc; t += 64)
        win[wwid][t] = sorted2[W0 + t];

    const int4* row = (const int4*)emb16;
    const int pb = beg - W0;
    const int d = end - beg;
    int dmax = d;
    dmax = max(dmax, __shfl_xor(dmax, 8, 64));
    dmax = max(dmax, __shfl_xor(dmax, 16, 64));
    dmax = max(dmax, __shfl_xor(dmax, 32, 64));

    float acc[8] = {0.f, 0.f, 0.f, 0.f, 0.f, 0.f, 0.f, 0.f};

    int e = 0;
    for (; e + 8 <= dmax; e += 8) {
        int idx[8];
        #pragma unroll
        for (int k = 0; k < 8; ++k) {
            int p = pb + e + k;
            int v = win[wwid][min(p, WIN - 1)];
            if (p >= WIN) v = sorted2[W0 + min(p, T - 1)];   // rare overflow
            idx[k] = v;
        }
        int4 u[8];
        #pragma unroll
        for (int k = 0; k < 8; ++k)
            u[k] = (e + k < d) ? row[idx[k] * 8 + c] : make_int4(0, 0, 0, 0);
        #pragma unroll
        for (int k = 0; k < 8; ++k) {
            acc[0] += bl16(u[k].x); acc[1] += bh16(u[k].x);
            acc[2] += bl16(u[k].y); acc[3] += bh16(u[k].y);
            acc[4] += bl16(u[k].z); acc[5] += bh16(u[k].z);
            acc[6] += bl16(u[k].w); acc[7] += bh16(u[k].w);
        }
    }
    for (; e < dmax; ++e) {
        int p = pb + e;
        int v = win[wwid][min(p, WIN - 1)];
        if (p >= WIN) v = sorted2[W0 + min(p, T - 1)];
        if (e < d) {
            int4 u0 = row[v * 8 + c];
            acc[0] += bl16(u0.x); acc[1] += bh16(u0.x);
            acc[2] += bl16(u0.y); acc[3] += bh16(u0.y);
            acc[4] += bl16(u0.z); acc[5] += bh16(u0.z);
            acc[6] += bl16(u0.w); acc[7] += bh16(u0.w);
        }
    }

    if (n < n_nodes) {
        f32x4* out4 = (f32x4*)out;
        f32x4 o0 = {acc[0], acc[1], acc[2], acc[3]};
        f32x4 o1 = {acc[4], acc[5], acc[6], acc[7]};
        __builtin_nontemporal_store(o0, out4 + (size_t)n * D4 + c * 2);
        __builtin_nontemporal_store(o1, out4 + (size_t)n * D4 + c * 2 + 1);
    }
}

// ---------- Fallback: atomic scatter ----------
__global__ void zero_out_kernel(float* __restrict__ out, int total4) {
    int i = blockIdx.x * blockDim.x + threadIdx.x;
    if (i < total4) ((float4*)out)[i] = make_float4(0.f, 0.f, 0.f, 0.f);
}

__global__ void scatter_fused_kernel(const float* __restrict__ x,
                                     const float* __restrict__ w,
                                     const int* __restrict__ src,
                                     const int* __restrict__ dst,
                                     float* __restrict__ out, int n_edges) {
    int t = blockIdx.x * blockDim.x + threadIdx.x;
    int e = t >> 4;
    int c = t & 15;
    if (e >= n_edges) return;
    int s = src[e];
    int d = dst[e];
    float4 xv = ((const float4*)x)[s * D4 + c];
    float4 wv = ((const float4*)w)[c];
    float* o = out + d * D + c * 4;
    unsafeAtomicAdd(o + 0, elu1(xv.x * wv.x));
    unsafeAtomicAdd(o + 1, elu1(xv.y * wv.y));
    unsafeAtomicAdd(o + 2, elu1(xv.z * wv.z));
    unsafeAtomicAdd(o + 3, elu1(xv.w * wv.w));
}

extern "C" void kernel_launch(void* const* d_in, const int* in_sizes, int n_in,
                              void* d_out, int out_size, void* d_ws, size_t ws_size,
                              hipStream_t stream) {
    const float* x   = (const float*)d_in[0];   // [N, 64] fp32
    const float* w   = (const float*)d_in[1];   // [1, 64] fp32
    const int*   src = (const int*)d_in[2];     // [E] int32
    const int*   dst = (const int*)d_in[3];     // [E] int32
    float* out = (float*)d_out;

    const int n_nodes = in_sizes[0] / D;
    const int n_edges = in_sizes[2];
    const int total4  = n_nodes * D4;
    const int total8  = n_nodes * 8;
    const int block = 256;

    const int NSB = (n_nodes + SBROWS - 1) >> SBSHIFT;
    const int NCH = (n_edges + CHUNK_E - 1) / CHUNK_E;

    auto align16 = [](size_t v) { return (v + 15) & ~size_t(15); };
    const size_t emb_b      = align16((size_t)n_nodes * D * 2);          // bf16
    const size_t slots_b    = align16((size_t)NCH * CHUNK_E * 4);
    const size_t cbase_b    = align16((size_t)NCH * (NSB + 1) * 4);
    const size_t sorted2_b  = align16((size_t)n_edges * 4);
    const size_t nodeoff_b  = align16((size_t)(n_nodes + 1) * 4);
    const size_t need = emb_b + slots_b + cbase_b + sorted2_b + nodeoff_b;

    if (ws_size >= need && n_nodes <= 131072 && NSB <= NSB_MAX && NCH <= NCH_MAX) {
        char* p = (char*)d_ws;
        unsigned int* emb16 = (unsigned int*)p;  p += emb_b;
        int* slots_lin = (int*)p;  p += slots_b;
        int* cbase     = (int*)p;  p += cbase_b;
        int* sorted2   = (int*)p;  p += sorted2_b;
        int* node_off  = (int*)p;

        chunk_emb_kernel<<<NCH, 512, 0, stream>>>(
            x, w, (uint4*)emb16, src, dst, slots_lin, cbase,
            total8, n_edges, NSB);
        fine_sort_kernel<<<NSB, 512, 0, stream>>>(
            slots_lin, cbase, sorted2, node_off, n_nodes, NCH, NSB);
        const int nwaves = (n_nodes + 7) / 8;
        const int gblocks = (nwaves * 64 + block - 1) / block;
        gather_sum_kernel<<<gblocks, block, 0, stream>>>(
            emb16, sorted2, node_off, out, n_nodes);
    } else {
        zero_out_kernel<<<(total4 + block - 1) / block, block, 0, stream>>>(out, total4);
        const int nt = n_edges * 16;
        scatter_fused_kernel<<<(nt + block - 1) / block, block, 0, stream>>>(
            x, w, src, dst, out, n_edges);
    }
}

// Round 12
// 142.246 us; speedup vs baseline: 4.2592x; 1.0126x over previous
//
#include <hip/hip_runtime.h>

#define D 64
#define D4 (D / 4)         // 16 float4 per fp32 row
#define SBSHIFT 8          // 256 nodes per super-bucket
#define SBROWS 256
#define CHUNK_E 4096       // edges per chunk_sort block
#define STAGE_CAP 4608     // fine_sort staging entries
#define NCH_MAX 512
#define NSB_MAX 512

typedef float f32x4 __attribute__((ext_vector_type(4)));

__device__ __forceinline__ float elu1(float z) {
    return z > 0.0f ? z : expm1f(z);
}

// pack two fp32 -> bf16 pair (RNE), a in low 16, b in high 16
__device__ __forceinline__ unsigned int bfpair(float a, float b) {
    unsigned int ua = __float_as_uint(a);
    unsigned int ub = __float_as_uint(b);
    ua = (ua + 0x7FFFu + ((ua >> 16) & 1u)) >> 16;
    ub = (ub + 0x7FFFu + ((ub >> 16) & 1u)) & 0xFFFF0000u;
    return ub | ua;
}

__device__ __forceinline__ float bl16(int u) {
    return __uint_as_float((unsigned)u << 16);
}
__device__ __forceinline__ float bh16(int u) {
    return __uint_as_float((unsigned)u & 0xFFFF0000u);
}

// ---------- K1: fused emb (grid-stride phase 0) + per-chunk LDS bucket sort ---
__global__ __launch_bounds__(512) void chunk_emb_kernel(
        const float* __restrict__ x, const float* __restrict__ w,
        uint4* __restrict__ emb16,
        const int* __restrict__ src, const int* __restrict__ dst,
        int* __restrict__ slots_lin,
        int* __restrict__ cbase,
        int total8, int n_edges, int NSB) {
    __shared__ int hist[NSB_MAX], base[NSB_MAX], cur[NSB_MAX];
    __shared__ int wsum[8];
    __shared__ int stage[CHUNK_E];      // 16 KB
    const int tid = threadIdx.x;
    const int lane = tid & 63, wid = tid >> 6;

    // ---- phase 0: emb16 = bf16(elu(x*w)), grid-stride ----
    hist[tid] = 0;
    const int gsz = gridDim.x * 512;
    for (int i = blockIdx.x * 512 + tid; i < total8; i += gsz) {
        f32x4 a = __builtin_nontemporal_load((const f32x4*)x + 2 * i);
        f32x4 b = __builtin_nontemporal_load((const f32x4*)x + 2 * i + 1);
        float4 wa = ((const float4*)w)[(2 * i) & 15];
        float4 wb = ((const float4*)w)[(2 * i + 1) & 15];
        uint4 o;
        o.x = bfpair(elu1(a.x * wa.x), elu1(a.y * wa.y));
        o.y = bfpair(elu1(a.z * wa.z), elu1(a.w * wa.w));
        o.z = bfpair(elu1(b.x * wb.x), elu1(b.y * wb.y));
        o.w = bfpair(elu1(b.z * wb.z), elu1(b.w * wb.w));
        emb16[i] = o;
    }

    // ---- chunk sort ----
    const int c0  = blockIdx.x * CHUNK_E;
    const int kn  = min(CHUNK_E, n_edges - c0);
    const int kn4 = kn >> 2;
    const int tail = kn & 3;
    __syncthreads();
    const int4* dst4 = (const int4*)(dst + c0);
    for (int k = tid; k < kn4; k += 512) {
        int4 dv = dst4[k];
        atomicAdd(&hist[dv.x >> SBSHIFT], 1);
        atomicAdd(&hist[dv.y >> SBSHIFT], 1);
        atomicAdd(&hist[dv.z >> SBSHIFT], 1);
        atomicAdd(&hist[dv.w >> SBSHIFT], 1);
    }
    if (tid < tail)
        atomicAdd(&hist[dst[c0 + (kn4 << 2) + tid] >> SBSHIFT], 1);
    __syncthreads();
    int h = hist[tid];
    int incl = h;
    #pragma unroll
    for (int off = 1; off < 64; off <<= 1) {
        int t = __shfl_up(incl, off, 64);
        if (lane >= off) incl += t;
    }
    if (lane == 63) wsum[wid] = incl;
    __syncthreads();
    {
        int pre = 0;
        for (int k = 0; k < wid; k++) pre += wsum[k];
        int e = pre + incl - h;
        base[tid] = e;
        cur[tid]  = e;
    }
    __syncthreads();
    const int4* src4 = (const int4*)(src + c0);
    for (int k = tid; k < kn4; k += 512) {
        int4 dv = dst4[k];
        int4 sv = src4[k];
        int pos;
        pos = atomicAdd(&cur[dv.x >> SBSHIFT], 1);
        stage[pos] = ((dv.x & (SBROWS - 1)) << 17) | sv.x;
        pos = atomicAdd(&cur[dv.y >> SBSHIFT], 1);
        stage[pos] = ((dv.y & (SBROWS - 1)) << 17) | sv.y;
        pos = atomicAdd(&cur[dv.z >> SBSHIFT], 1);
        stage[pos] = ((dv.z & (SBROWS - 1)) << 17) | sv.z;
        pos = atomicAdd(&cur[dv.w >> SBSHIFT], 1);
        stage[pos] = ((dv.w & (SBROWS - 1)) << 17) | sv.w;
    }
    if (tid < tail) {
        int k = (kn4 << 2) + tid;
        int d = dst[c0 + k], s = src[c0 + k];
        int pos = atomicAdd(&cur[d >> SBSHIFT], 1);
        stage[pos] = ((d & (SBROWS - 1)) << 17) | s;
    }
    __syncthreads();
    for (int j = tid; j < kn; j += 512)
        slots_lin[c0 + j] = stage[j];
    if (tid < NSB) cbase[blockIdx.x * (NSB + 1) + tid] = base[tid];
    if (tid == 0)  cbase[blockIdx.x * (NSB + 1) + NSB] = kn;
}

// ---------- K2: per-sb LDS counting sort -> sorted2 + node_off ----
__global__ __launch_bounds__(512) void fine_sort_kernel(
        const int* __restrict__ slots_lin,
        const int* __restrict__ cbase,
        int* __restrict__ sorted2,
        int* __restrict__ node_off,
        int n_nodes, int NCH, int NSB) {
    __shared__ int rstart[NCH_MAX], rc[NCH_MAX];
    __shared__ int counts[SBROWS], cur[SBROWS];
    __shared__ int wsum[4], swa[8], swt[8];
    __shared__ int stage_out[STAGE_CAP];   // 18 KB
    const int s = blockIdx.x;
    const int tid = threadIdx.x;
    const int wid = tid >> 6, lane = tid & 63;
    const int sg = tid >> 4, l16 = tid & 15;

    int va = 0, vt = 0;
    if (tid < NCH) {
        int a = cbase[tid * (NSB + 1) + s];
        int b = cbase[tid * (NSB + 1) + s + 1];
        rstart[tid] = tid * CHUNK_E + a;
        rc[tid] = b - a;
        va = a;
        vt = b - a;
    }
    #pragma unroll
    for (int off = 1; off < 64; off <<= 1) {
        va += __shfl_xor(va, off, 64);
        vt += __shfl_xor(vt, off, 64);
    }
    if (lane == 0) { swa[wid] = va; swt[wid] = vt; }
    if (tid < SBROWS) counts[tid] = 0;
    __syncthreads();
    int sbb = 0, T = 0;
    #pragma unroll
    for (int k = 0; k < 8; k++) { sbb += swa[k]; T += swt[k]; }
    const bool fast = (T <= STAGE_CAP);
    for (int c = sg; c < NCH; c += 32) {
        int n = rc[c], st = rstart[c];
        for (int j = l16; j < n; j += 16)
            atomicAdd(&counts[((unsigned)slots_lin[st + j]) >> 17], 1);
    }
    __syncthreads();
    int v = 0, incl = 0;
    if (tid < SBROWS) {
        v = counts[tid];
        incl = v;
        #pragma unroll
        for (int off = 1; off < 64; off <<= 1) {
            int t = __shfl_up(incl, off, 64);
            if (lane >= off) incl += t;
        }
        if (lane == 63) wsum[wid] = incl;
    }
    __syncthreads();
    if (tid < SBROWS) {
        int pre = 0;
        for (int k = 0; k < wid; k++) pre += wsum[k];
        int e0 = pre + incl - v;
        cur[tid] = fast ? e0 : sbb + e0;
        int g0 = (s << SBSHIFT) + tid;
        if (g0 < n_nodes) node_off[g0] = sbb + e0;
    }
    if (s == gridDim.x - 1 && tid == 0) node_off[n_nodes] = sbb + T;
    __syncthreads();
    for (int c = sg; c < NCH; c += 32) {
        int n = rc[c], st = rstart[c];
        for (int j = l16; j < n; j += 16) {
            int pl = slots_lin[st + j];
            int r2 = ((unsigned)pl) >> 17;
            int pos = atomicAdd(&cur[r2], 1);
            if (fast) stage_out[pos] = pl & 0x1FFFF;
            else      sorted2[pos]   = pl & 0x1FFFF;
        }
    }
    __syncthreads();
    if (fast) {
        for (int i = tid; i < T; i += 512)
            sorted2[sbb + i] = stage_out[i];
    }
}

// ---------- K3: 8 nodes per wave, 8 lanes per node.  Lane-local accumulation.
//   CORRECTNESS INVARIANT: every __shfl executes with ALL 64 lanes active —
//   loop bound is the wave-uniform dmax (max over the 8 node groups), window
//   position p clamped to [0, T-1]; only the row-load+accumulate is
//   predicated on e < d. ----------
__device__ __forceinline__ int pick_idx(int p, int m0, int m1, int m2,
                                        const int* __restrict__ s2, int W0) {
    int a  = __shfl(m0, p & 63, 64);
    int b  = __shfl(m1, p & 63, 64);
    int cc = __shfl(m2, p & 63, 64);
    int r = p < 64 ? a : (p < 128 ? b : cc);
    if (p >= 192) r = s2[W0 + p];   // rare overflow, p < T so in range
    return r;
}

__global__ void gather_sum_kernel(const unsigned int* __restrict__ emb16,
                                  const int* __restrict__ sorted2,
                                  const int* __restrict__ node_off,
                                  float* __restrict__ out, int n_nodes) {
    const int wv = (blockIdx.x * blockDim.x + threadIdx.x) >> 6;
    const int lane = threadIdx.x & 63;
    const int g = lane >> 3;          // node slot within wave (8 nodes/wave)
    const int c = lane & 7;           // int4 chunk within 128B row
    const int n0 = wv * 8;
    if (n0 >= n_nodes) return;        // wave-uniform exit
    const int n = n0 + g;

    int beg = 0, end = 0;
    if (n < n_nodes) {
        beg = node_off[n];
        end = node_off[n + 1];
    }
    const int W0   = node_off[n0];                        // broadcast load
    const int Wend = node_off[min(n0 + 8, n_nodes)];      // broadcast load
    const int T = Wend - W0;

    // coalesced preload of the wave's contiguous edge window (up to 192)
    int m0 = 0, m1 = 0, m2 = 0;
    if (lane < T)       m0 = sorted2[W0 + lane];
    if (64 + lane < T)  m1 = sorted2[W0 + 64 + lane];
    if (128 + lane < T) m2 = sorted2[W0 + 128 + lane];

    const int4* row = (const int4*)emb16;
    const int pb = beg - W0;
    const int d = end - beg;
    // wave-uniform trip count: max degree over the 8 groups (d uniform in-group)
    int dmax = d;
    dmax = max(dmax, __shfl_xor(dmax, 8, 64));
    dmax = max(dmax, __shfl_xor(dmax, 16, 64));
    dmax = max(dmax, __shfl_xor(dmax, 32, 64));
    const int pclamp = T - 1;

    float acc[8] = {0.f, 0.f, 0.f, 0.f, 0.f, 0.f, 0.f, 0.f};

    int e = 0;
    for (; e + 4 <= dmax; e += 4) {
        int p0 = min(max(pb + e,     0), pclamp);
        int p1 = min(max(pb + e + 1, 0), pclamp);
        int p2 = min(max(pb + e + 2, 0), pclamp);
        int p3 = min(max(pb + e + 3, 0), pclamp);
        int i0 = pick_idx(p0, m0, m1, m2, sorted2, W0);
        int i1 = pick_idx(p1, m0, m1, m2, sorted2, W0);
        int i2 = pick_idx(p2, m0, m1, m2, sorted2, W0);
        int i3 = pick_idx(p3, m0, m1, m2, sorted2, W0);
        int4 u0 = make_int4(0, 0, 0, 0);
        int4 u1 = make_int4(0, 0, 0, 0);
        int4 u2 = make_int4(0, 0, 0, 0);
        int4 u3 = make_int4(0, 0, 0, 0);
        if (e < d)     u0 = row[i0 * 8 + c];
        if (e + 1 < d) u1 = row[i1 * 8 + c];
        if (e + 2 < d) u2 = row[i2 * 8 + c];
        if (e + 3 < d) u3 = row[i3 * 8 + c];
        acc[0] += bl16(u0.x) + bl16(u1.x) + bl16(u2.x) + bl16(u3.x);
        acc[1] += bh16(u0.x) + bh16(u1.x) + bh16(u2.x) + bh16(u3.x);
        acc[2] += bl16(u0.y) + bl16(u1.y) + bl16(u2.y) + bl16(u3.y);
        acc[3] += bh16(u0.y) + bh16(u1.y) + bh16(u2.y) + bh16(u3.y);
        acc[4] += bl16(u0.z) + bl16(u1.z) + bl16(u2.z) + bl16(u3.z);
        acc[5] += bh16(u0.z) + bh16(u1.z) + bh16(u2.z) + bh16(u3.z);
        acc[6] += bl16(u0.w) + bl16(u1.w) + bl16(u2.w) + bl16(u3.w);
        acc[7] += bh16(u0.w) + bh16(u1.w) + bh16(u2.w) + bh16(u3.w);
    }
    for (; e < dmax; ++e) {
        int p0 = min(max(pb + e, 0), pclamp);
        int i0 = pick_idx(p0, m0, m1, m2, sorted2, W0);
        if (e < d) {
            int4 u0 = row[i0 * 8 + c];
            acc[0] += bl16(u0.x); acc[1] += bh16(u0.x);
            acc[2] += bl16(u0.y); acc[3] += bh16(u0.y);
            acc[4] += bl16(u0.z); acc[5] += bh16(u0.z);
            acc[6] += bl16(u0.w); acc[7] += bh16(u0.w);
        }
    }

    if (n < n_nodes) {
        f32x4* out4 = (f32x4*)out;
        f32x4 o0 = {acc[0], acc[1], acc[2], acc[3]};
        f32x4 o1 = {acc[4], acc[5], acc[6], acc[7]};
        __builtin_nontemporal_store(o0, out4 + (size_t)n * D4 + c * 2);
        __builtin_nontemporal_store(o1, out4 + (size_t)n * D4 + c * 2 + 1);
    }
}

// ---------- Fallback: atomic scatter ----------
__global__ void zero_out_kernel(float* __restrict__ out, int total4) {
    int i = blockIdx.x * blockDim.x + threadIdx.x;
    if (i < total4) ((float4*)out)[i] = make_float4(0.f, 0.f, 0.f, 0.f);
}

__global__ void scatter_fused_kernel(const float* __restrict__ x,
                                     const float* __restrict__ w,
                                     const int* __restrict__ src,
                                     const int* __restrict__ dst,
                                     float* __restrict__ out, int n_edges) {
    int t = blockIdx.x * blockDim.x + threadIdx.x;
    int e = t >> 4;
    int c = t & 15;
    if (e >= n_edges) return;
    int s = src[e];
    int d = dst[e];
    float4 xv = ((const float4*)x)[s * D4 + c];
    float4 wv = ((const float4*)w)[c];
    float* o = out + d * D + c * 4;
    unsafeAtomicAdd(o + 0, elu1(xv.x * wv.x));
    unsafeAtomicAdd(o + 1, elu1(xv.y * wv.y));
    unsafeAtomicAdd(o + 2, elu1(xv.z * wv.z));
    unsafeAtomicAdd(o + 3, elu1(xv.w * wv.w));
}

extern "C" void kernel_launch(void* const* d_in, const int* in_sizes, int n_in,
                              void* d_out, int out_size, void* d_ws, size_t ws_size,
                              hipStream_t stream) {
    const float* x   = (const float*)d_in[0];   // [N, 64] fp32
    const float* w   = (const float*)d_in[1];   // [1, 64] fp32
    const int*   src = (const int*)d_in[2];     // [E] int32
    const int*   dst = (const int*)d_in[3];     // [E] int32
    float* out = (float*)d_out;

    const int n_nodes = in_sizes[0] / D;
    const int n_edges = in_sizes[2];
    const int total4  = n_nodes * D4;
    const int total8  = n_nodes * 8;
    const int block = 256;

    const int NSB = (n_nodes + SBROWS - 1) >> SBSHIFT;
    const int NCH = (n_edges + CHUNK_E - 1) / CHUNK_E;

    auto align16 = [](size_t v) { return (v + 15) & ~size_t(15); };
    const size_t emb_b      = align16((size_t)n_nodes * D * 2);          // bf16
    const size_t slots_b    = align16((size_t)NCH * CHUNK_E * 4);
    const size_t cbase_b    = align16((size_t)NCH * (NSB + 1) * 4);
    const size_t sorted2_b  = align16((size_t)n_edges * 4);
    const size_t nodeoff_b  = align16((size_t)(n_nodes + 1) * 4);
    const size_t need = emb_b + slots_b + cbase_b + sorted2_b + nodeoff_b;

    if (ws_size >= need && n_nodes <= 131072 && NSB <= NSB_MAX && NCH <= NCH_MAX) {
        char* p = (char*)d_ws;
        unsigned int* emb16 = (unsigned int*)p;  p += emb_b;
        int* slots_lin = (int*)p;  p += slots_b;
        int* cbase     = (int*)p;  p += cbase_b;
        int* sorted2   = (int*)p;  p += sorted2_b;
        int* node_off  = (int*)p;

        chunk_emb_kernel<<<NCH, 512, 0, stream>>>(
            x, w, (uint4*)emb16, src, dst, slots_lin, cbase,
            total8, n_edges, NSB);
        fine_sort_kernel<<<NSB, 512, 0, stream>>>(
            slots_lin, cbase, sorted2, node_off, n_nodes, NCH, NSB);
        const int nwaves = (n_nodes + 7) / 8;
        const int gblocks = (nwaves * 64 + block - 1) / block;
        gather_sum_kernel<<<gblocks, block, 0, stream>>>(
            emb16, sorted2, node_off, out, n_nodes);
    } else {
        zero_out_kernel<<<(total4 + block - 1) / block, block, 0, stream>>>(out, total4);
        const int nt = n_edges * 16;
        scatter_fused_kernel<<<(nt + block - 1) / block, block, 0, stream>>>(
            x, w, src, dst, out, n_edges);
    }
}